// Round 19
// baseline (29.870 us; speedup 1.0000x reference)
//
#include <hip/hip_runtime.h>
#include <math.h>

#define BATCH 256
#define CIN   3
#define COUT  16
#define DI    16
#define HI    32
#define WI    32

typedef _Float16 f16;
typedef f16   f16x4 __attribute__((ext_vector_type(4)));
typedef f16   f16x8 __attribute__((ext_vector_type(8)));
typedef float f32x4 __attribute__((ext_vector_type(4)));

#define LOG2E 1.44269504088896340736f

// LDS slab (f16 units): xs[dd][hh][w][ci], ci stride 1 (3 cin + pad),
// w stride 4, row stride ROWU=144 f16 (288B), plane stride PLANEU=4320.
// 288B ≡ 32 mod 128 -> conflict-free B reads (R5/R11: ~700K conflicts).
// PAD SLOTS HOLD 1.0: every ci-pad K-slot has A==0 in all MFMAs EXCEPT
// g8/kq0/j3, whose W-side value = bias*log2e -> bias via the matrix pipe.
#define ROWU   144
#define PLANEU 4320
#define XS_N   (6 * PLANEU)              // 51840 B -> 3 WG/CU (24 waves/CU @512thr)
#define G8OFF  (2 * PLANEU + 2 * ROWU)   // (kd=2,kh=2) row offset

#define SV8(a, b) __builtin_shufflevector(a, b, 0, 1, 2, 3, 4, 5, 6, 7)
#define MFMA16(A, B, C) __builtin_amdgcn_mfma_f32_16x16x32_f16(A, B, C, 0, 0, 0)

// VALU-pipe reductions over the 16-lane row (DPP row_ror), proven since R8.
#define DPPMAX(v, ctrl) do {                                                  \
    int t_ = __builtin_amdgcn_update_dpp(                                     \
        0, __builtin_bit_cast(int, v), (ctrl), 0xF, 0xF, false);              \
    v = fmaxf(v, __builtin_bit_cast(float, t_));                              \
} while (0)

// 16-lane-row sum butterfly: ror8+ror4+ror2+ror1 -> every lane holds the
// total of its row. Association order differs per lane (~1 ulp) -- fine.
#define DPPSUM(v) do {                                                        \
    int q8_ = __builtin_amdgcn_update_dpp(                                    \
        0, __builtin_bit_cast(int, v), 0x128, 0xF, 0xF, false);               \
    v += __builtin_bit_cast(float, q8_);                                      \
    int q4_ = __builtin_amdgcn_update_dpp(                                    \
        0, __builtin_bit_cast(int, v), 0x124, 0xF, 0xF, false);               \
    v += __builtin_bit_cast(float, q4_);                                      \
    int q2_ = __builtin_amdgcn_update_dpp(                                    \
        0, __builtin_bit_cast(int, v), 0x122, 0xF, 0xF, false);               \
    v += __builtin_bit_cast(float, q2_);                                      \
    int q1_ = __builtin_amdgcn_update_dpp(                                    \
        0, __builtin_bit_cast(int, v), 0x121, 0xF, 0xF, false);               \
    v += __builtin_bit_cast(float, q1_);                                      \
} while (0)

// 8 ds_read_b64 into NAMED set P0..P7 (rule #20: static names, no arrays)
#define LOADS(P, dp)                                                          \
    P##0 = *(const f16x4*)(a1 + (dp));                                        \
    P##1 = *(const f16x4*)(a2 + (dp));                                        \
    P##2 = *(const f16x4*)(a1 + (dp) + 4);                                    \
    P##3 = *(const f16x4*)(a2 + (dp) + 4);                                    \
    P##4 = *(const f16x4*)(a1 + (dp) + 8);                                    \
    P##5 = *(const f16x4*)(a2 + (dp) + 8);                                    \
    P##6 = *(const f16x4*)(a3 + (dp));                                        \
    P##7 = *(const f16x4*)(a3 + (dp) + 4);

// SWAPPED-OPERAND MFMA: A = x fragments (M=positions), B = weights (N=couts).
// Same per-lane fragment data as before (A row and B col are both lane&15).
// Output: cout = lane&15, position-in-cell = 4*kq + reg. Softmax over couts
// is now a 16-lane-row reduction -> VALU DPP butterfly, NO LDS-pipe shuffles
// in the inner loop (R15 had 2 serial ~120cyc shfl_xor per (cell,d)).
#define COMPUTE(P)  do {                                                      \
    f32x4 a_ = {0.f, 0.f, 0.f, 0.f};                                          \
    a_ = MFMA16(SV8(P##0, P##1), wm[0], a_);                                  \
    a_ = MFMA16(SV8(P##2, P##3), wm[1], a_);                                  \
    a_ = MFMA16(SV8(P##4, P##5), wm[2], a_);                                  \
    a_ = MFMA16(SV8(P##6, P##7), wg,    a_);  /* includes +bias via k=3 */    \
    float e0 = __builtin_amdgcn_exp2f(a_[0]);                                 \
    float e1 = __builtin_amdgcn_exp2f(a_[1]);                                 \
    float e2 = __builtin_amdgcn_exp2f(a_[2]);                                 \
    float e3 = __builtin_amdgcn_exp2f(a_[3]);                                 \
    float s0 = e0, s1 = e1, s2 = e2, s3 = e3;                                 \
    DPPSUM(s0);                                                               \
    DPPSUM(s1);                                                               \
    DPPSUM(s2);                                                               \
    DPPSUM(s3);                                                               \
    pm[0] = fmaxf(pm[0], e0 * __builtin_amdgcn_rcpf(s0));                     \
    pm[1] = fmaxf(pm[1], e1 * __builtin_amdgcn_rcpf(s1));                     \
    pm[2] = fmaxf(pm[2], e2 * __builtin_amdgcn_rcpf(s2));                     \
    pm[3] = fmaxf(pm[3], e3 * __builtin_amdgcn_rcpf(s3));                     \
} while (0)

// ---------------------------------------------------------------------------
// Fused conv3d + bias + channel-softmax + 4^3 maxpool.
// One 512-thread WG per (b,pd); 768 WGs = 3 WG/CU = 24 waves/CU, ONE barrier.
// Named 2-stage pipeline over d (R15); swapped MFMA operands put the softmax
// reduction on the VALU pipe (this round's single change).
// ---------------------------------------------------------------------------
__global__ __launch_bounds__(512, 6) void conv_sm_pool_mfma(
    const float* __restrict__ x, const float* __restrict__ W,
    const float* __restrict__ bias, float* __restrict__ out)
{
    __shared__ __align__(16) f16 xs[XS_N];

    const int tid  = threadIdx.x;
    const int lane = tid & 63;
    const int wave = tid >> 6;           // 0..7
    const int b    = blockIdx.x / 3;
    const int pd   = blockIdx.x % 3;
    const int d0   = pd * 4;

    const int col = lane & 15;     // x-fragment position-in-cell (hl*4+wl); also cout of D
    const int kq  = lane >> 4;     // K-slot group

    // ---- W gather -> weight fragments (B operand), PRE-SCALED by log2e ----
    // k = g*4 + ci, g = kd*3+kh; this lane holds groups 2kq, 2kq+1; N-col = col.
    const float* wc  = W + col * 81;
    const float* wqp = wc + kq * 6;
    f16x8 wm[3];
    #pragma unroll
    for (int kw = 0; kw < 3; ++kw) {
        #pragma unroll
        for (int j = 0; j < 8; ++j) {
            const int ci = j & 3, jj = j >> 2;
            float v = (ci < 3) ? wqp[ci * 27 + 3 * jj + kw] * LOG2E : 0.f;
            wm[kw][j] = (f16)v;
        }
    }
    f16x8 wg = {};
    if (kq == 0) {
        #pragma unroll
        for (int j = 0; j < 8; ++j) {
            const int ci = j & 3, kw = j >> 2;
            if (ci < 3) wg[j] = (f16)(wc[ci * 27 + 24 + kw] * LOG2E);
        }
        wg[3] = (f16)(bias[col] * LOG2E);   // bias slot (x pad staged as 1.0)
    } else if (kq == 1) {
        #pragma unroll
        for (int j = 0; j < 3; ++j) wg[j] = (f16)(wc[j * 27 + 26] * LOG2E);
    }

    // ---- Stage x[b,:,d0..d0+5,0..29,0..31] -> f16 LDS; ci-pad = 1.0 ----
    for (int i = tid; i < 1440; i += 512) {              // 6 dd * 30 hh * 8 wq
        int wqd = i & 7;
        int r   = i >> 3;
        int hh  = r % 30;
        int dd  = r / 30;
        const float* px = x + ((size_t)b * 48 + (d0 + dd)) * 1024 + hh * 32 + wqd * 4;
        float4 v0 = *(const float4*)(px);
        float4 v1 = *(const float4*)(px + 16384);
        float4 v2 = *(const float4*)(px + 32768);
        f16x8 p0, p1;
        p0[0] = (f16)v0.x; p0[1] = (f16)v1.x; p0[2] = (f16)v2.x; p0[3] = (f16)1.f;
        p0[4] = (f16)v0.y; p0[5] = (f16)v1.y; p0[6] = (f16)v2.y; p0[7] = (f16)1.f;
        p1[0] = (f16)v0.z; p1[1] = (f16)v1.z; p1[2] = (f16)v2.z; p1[3] = (f16)1.f;
        p1[4] = (f16)v0.w; p1[5] = (f16)v1.w; p1[6] = (f16)v2.w; p1[7] = (f16)1.f;
        f16* dst = xs + ((dd * 30 + hh) * 36 + wqd * 4) * 4;
        *(f16x8*)(dst)     = p0;
        *(f16x8*)(dst + 8) = p1;
    }

    // per-lane x-read invariants (unchanged: A row index is still lane&15)
    const int g0   = kq * 2;
    const int off1 = (g0 / 3) * PLANEU + (g0 % 3) * ROWU;
    const int off2 = ((g0 + 1) / 3) * PLANEU + ((g0 + 1) % 3) * ROWU;
    const int hl = col >> 2, wl = col & 3;
    const int spat  = hl * ROWU + wl * 4;
    const int g8sel = (kq == 0) ? 0 : 8;

    __syncthreads();   // the only barrier

    for (int c = wave; c < 49; c += 8) {    // cell = ch*7 + pw, ~6 per wave
        const int ch = c / 7;
        const int pw = c - ch * 7;
        const f16* base = xs + ch * 4 * ROWU + pw * 16 + spat;
        const f16* a1 = base + off1;
        const f16* a2 = base + off2;
        const f16* a3 = base + G8OFF + g8sel;

        f32x4 pm = {0.f, 0.f, 0.f, 0.f};

        // named 2-stage pipeline over the 4 d-slices:
        // LA(0) LB(1) CA LA(2) CB LB(3) CA CB
        f16x4 A0, A1, A2, A3, A4, A5, A6, A7;
        f16x4 B0, B1, B2, B3, B4, B5, B6, B7;
        LOADS(A, 0)
        LOADS(B, PLANEU)
        COMPUTE(A);                 // d=0 (B's d=1 loads in flight)
        LOADS(A, 2 * PLANEU)
        COMPUTE(B);                 // d=1 (A's d=2 loads in flight)
        LOADS(B, 3 * PLANEU)
        COMPUTE(A);                 // d=2 (B's d=3 loads in flight)
        COMPUTE(B);                 // d=3

        // ---- pool over the cell: 4 regs local, then lanes ^16, ^32 ----
        float m = fmaxf(fmaxf(pm[0], pm[1]), fmaxf(pm[2], pm[3]));
        m = fmaxf(m, __shfl_xor(m, 16));
        m = fmaxf(m, __shfl_xor(m, 32));

        if (lane < 16) {
            out[((size_t)b * COUT + col) * 147 + pd * 49 + c] = m;
        }
    }
}

extern "C" void kernel_launch(void* const* d_in, const int* in_sizes, int n_in,
                              void* d_out, int out_size, void* d_ws, size_t ws_size,
                              hipStream_t stream) {
    const float* x    = (const float*)d_in[0];
    const float* W    = (const float*)d_in[1];
    const float* bias = (const float*)d_in[2];
    float* out = (float*)d_out;

    conv_sm_pool_mfma<<<BATCH * 3, 512, 0, stream>>>(x, W, bias, out);
}